// Round 2
// baseline (7182.062 us; speedup 1.0000x reference)
//
#include <hip/hip_runtime.h>
#include <hip/hip_cooperative_groups.h>

namespace cg = cooperative_groups;

// GADBase diffusion: B=2, H=W=512, 128 iterations of fused diffuse+adjust,
// executed in a single persistent cooperative kernel with grid-wide syncs.
constexpr int Hh = 512, Ww = 512, Bn = 2;
constexpr int SWs = 128;                  // source/mask spatial size
constexpr float Lf = 0.24f;
constexpr float Kf = 0.03f;
constexpr float EPSf = 1e-8f;
constexpr int NSTEPS = 128;

constexpr int NPIX = Bn * Hh * Ww;        // 524288
constexpr int CVN  = Bn * (Hh - 1) * Ww;  // 523264

constexpr int TILE = 32;
constexpr int TPB  = Ww / TILE;           // 16 tiles per row
constexpr int NTILES = Bn * TPB * TPB;    // 512 workgroups
constexpr int SROW = 37;                  // LDS row stride (bank-conflict-free)

// ---------------------------------------------------------------------------
// Kernel 1: edge-stopping coefficients cv, ch (computed once, written to d_out).
// ---------------------------------------------------------------------------
__global__ __launch_bounds__(256) void cvch_kernel(
    const float* __restrict__ img, const float* __restrict__ guide,
    float* __restrict__ cv, float* __restrict__ ch) {
  int idx = blockIdx.x * blockDim.x + threadIdx.x;
  if (idx >= NPIX) return;
  int x = idx & (Ww - 1);
  int y = (idx >> 9) & (Hh - 1);
  int b = idx >> 18;
  const float inv_k2 = 1.0f / (Kf * Kf);
  const float* f0 = img + (size_t)b * Hh * Ww;
  const float* g0 = guide + (size_t)b * 3 * Hh * Ww;
  const float* g1 = g0 + Hh * Ww;
  const float* g2 = g1 + Hh * Ww;
  int p = y * Ww + x;
  float c0 = f0[p], c1 = g0[p], c2 = g1[p], c3 = g2[p];
  if (y < Hh - 1) {
    int q = p + Ww;
    float m = (fabsf(f0[q] - c0) + fabsf(g0[q] - c1) +
               fabsf(g1[q] - c2) + fabsf(g2[q] - c3)) * 0.25f;
    cv[(b * (Hh - 1) + y) * Ww + x] = 1.0f / (1.0f + m * m * inv_k2);
  }
  if (x < Ww - 1) {
    int q = p + 1;
    float m = (fabsf(f0[q] - c0) + fabsf(g0[q] - c1) +
               fabsf(g1[q] - c2) + fabsf(g2[q] - c3)) * 0.25f;
    ch[(b * Hh + y) * (Ww - 1) + x] = 1.0f / (1.0f + m * m * inv_k2);
  }
}

// ---------------------------------------------------------------------------
// Kernel 2: persistent cooperative kernel — all 128 steps.
// One WG per 32x32 tile (64 threads, 1 wave). Tile lives in LDS (ping-pong);
// only 1-px halo edges are exchanged through compact global buffers.
// Per-tile edge record (128 floats): [0:32)=top row, [32:64)=bottom row,
// [64:96)=left col, [96:128)=right col.
// ---------------------------------------------------------------------------
__global__ __launch_bounds__(64) void diffuse_all(
    const float* __restrict__ ybic, float* __restrict__ ypred,
    const float* __restrict__ cv, const float* __restrict__ ch,
    const float* __restrict__ source, const float* __restrict__ mask,
    float* __restrict__ hbuf0, float* __restrict__ hbuf1) {
  __shared__ float sbuf[2][34 * SROW];

  cg::grid_group grid = cg::this_grid();

  int wg = blockIdx.x;                 // 0..511
  int b  = wg >> 8;                    // 256 tiles per image
  int tb = wg & 255;
  int tyI = tb >> 4, txI = tb & 15;
  int ty0 = tyI * TILE, tx0 = txI * TILE;

  int tid = threadIdx.x;
  int bby = tid >> 3, bbx = tid & 7;   // thread -> one 4x4 block
  int py0 = bby * 4, px0 = bbx * 4;
  int gy0 = ty0 + py0, gx0 = tx0 + px0;

  const size_t ib = (size_t)b * Hh * Ww;
  const float* Isrc = ybic + ib;

  // --- step-invariant per-thread state (registers) ---
  const float* cvb = cv + (size_t)b * (Hh - 1) * Ww;
  const float* chb = ch + (size_t)b * Hh * (Ww - 1);
  float cvr[5][4];   // L*cv rows gy0-1..gy0+3, zero-padded at borders
  float chr[4][5];   // L*ch cols gx0-1..gx0+3, zero-padded at borders
#pragma unroll
  for (int r = 0; r < 5; ++r) {
    int row = gy0 - 1 + r;
    bool ok = (row >= 0 && row < Hh - 1);
#pragma unroll
    for (int dx = 0; dx < 4; ++dx)
      cvr[r][dx] = ok ? Lf * cvb[row * Ww + gx0 + dx] : 0.0f;
  }
#pragma unroll
  for (int dy = 0; dy < 4; ++dy) {
    int row = gy0 + dy;
#pragma unroll
    for (int c = 0; c < 5; ++c) {
      int col = gx0 - 1 + c;
      bool ok = (col >= 0 && col < Ww - 1);
      chr[dy][c] = ok ? Lf * chb[row * (Ww - 1) + col] : 0.0f;
    }
  }
  int sidx = (b * SWs + (gy0 >> 2)) * SWs + (gx0 >> 2);
  float srcv = source[sidx];
  bool msk = mask[sidx] > 0.5f;

  // --- stage interior tile into LDS ---
  float* sA = sbuf[0];
  float* sB = sbuf[1];
#pragma unroll
  for (int dy = 0; dy < 4; ++dy) {
    float4 t4 = *reinterpret_cast<const float4*>(&Isrc[(gy0 + dy) * Ww + gx0]);
    int base = (py0 + dy + 1) * SROW + px0 + 4;
    sA[base + 0] = t4.x; sA[base + 1] = t4.y;
    sA[base + 2] = t4.z; sA[base + 3] = t4.w;
  }

  for (int t = 0; t < NSTEPS; ++t) {
    // --- halo ring loads (2 per thread) ---
    const float* hb = (t & 1) ? hbuf0 : hbuf1;  // buffer written at step t-1
    if (tid < 32) {
      int i = tid;
      float tv = 0.0f, lv = 0.0f;
      if (ty0 > 0)
        tv = (t == 0) ? Isrc[(ty0 - 1) * Ww + tx0 + i]
                      : hb[(wg - TPB) * 128 + 32 + i];   // upper tile's bottom row
      if (tx0 > 0)
        lv = (t == 0) ? Isrc[(ty0 + i) * Ww + tx0 - 1]
                      : hb[(wg - 1) * 128 + 96 + i];     // left tile's right col
      sA[0 * SROW + 4 + i] = tv;
      sA[(1 + i) * SROW + 3] = lv;
    } else {
      int i = tid - 32;
      float bv = 0.0f, rv = 0.0f;
      if (ty0 + TILE < Hh)
        bv = (t == 0) ? Isrc[(ty0 + TILE) * Ww + tx0 + i]
                      : hb[(wg + TPB) * 128 + 0 + i];    // lower tile's top row
      if (tx0 + TILE < Ww)
        rv = (t == 0) ? Isrc[(ty0 + i) * Ww + tx0 + TILE]
                      : hb[(wg + 1) * 128 + 64 + i];     // right tile's left col
      sA[33 * SROW + 4 + i] = bv;
      sA[(1 + i) * SROW + 36] = rv;
    }
    __syncthreads();

    // --- 6x6 neighborhood into registers, branch-free 5-point stencil ---
    float n[6][6];
#pragma unroll
    for (int r = 0; r < 6; ++r)
#pragma unroll
      for (int c = 0; c < 6; ++c)
        n[r][c] = sA[(py0 + r) * SROW + px0 + 3 + c];

    float v[4][4];
    float sum = 0.0f;
#pragma unroll
    for (int dy = 0; dy < 4; ++dy)
#pragma unroll
      for (int dx = 0; dx < 4; ++dx) {
        float cc = n[dy + 1][dx + 1];
        float acc = cc
            + cvr[dy + 1][dx] * (n[dy + 2][dx + 1] - cc)
            - cvr[dy][dx]     * (cc - n[dy][dx + 1])
            + chr[dy][dx + 1] * (n[dy + 1][dx + 2] - cc)
            - chr[dy][dx]     * (cc - n[dy + 1][dx]);
        v[dy][dx] = acc;
        sum += acc;
      }

    // --- adjust: block mean -> ratio ---
    float ratio = msk ? 1.0f : srcv / (sum * (1.0f / 16.0f) + EPSf);
#pragma unroll
    for (int dy = 0; dy < 4; ++dy)
#pragma unroll
      for (int dx = 0; dx < 4; ++dx) v[dy][dx] *= ratio;

    if (t == NSTEPS - 1) {
      // final result straight from registers to d_out
#pragma unroll
      for (int dy = 0; dy < 4; ++dy)
        *reinterpret_cast<float4*>(&ypred[ib + (gy0 + dy) * Ww + gx0]) =
            make_float4(v[dy][0], v[dy][1], v[dy][2], v[dy][3]);
      break;
    }

    // --- store interior to other LDS buffer ---
#pragma unroll
    for (int dy = 0; dy < 4; ++dy) {
      int base = (py0 + dy + 1) * SROW + px0 + 4;
      sB[base + 0] = v[dy][0]; sB[base + 1] = v[dy][1];
      sB[base + 2] = v[dy][2]; sB[base + 3] = v[dy][3];
    }

    // --- publish tile edges for neighbors ---
    float* gw = ((t & 1) ? hbuf1 : hbuf0) + wg * 128;
    if (bby == 0)
      *reinterpret_cast<float4*>(&gw[0 + px0]) =
          make_float4(v[0][0], v[0][1], v[0][2], v[0][3]);
    if (bby == 7)
      *reinterpret_cast<float4*>(&gw[32 + px0]) =
          make_float4(v[3][0], v[3][1], v[3][2], v[3][3]);
    if (bbx == 0)
      *reinterpret_cast<float4*>(&gw[64 + py0]) =
          make_float4(v[0][0], v[1][0], v[2][0], v[3][0]);
    if (bbx == 7)
      *reinterpret_cast<float4*>(&gw[96 + py0]) =
          make_float4(v[0][3], v[1][3], v[2][3], v[3][3]);

    grid.sync();

    float* tmp = sA; sA = sB; sB = tmp;
  }
}

// ---------------------------------------------------------------------------
extern "C" void kernel_launch(void* const* d_in, const int* in_sizes, int n_in,
                              void* d_out, int out_size, void* d_ws, size_t ws_size,
                              hipStream_t stream) {
  const float* guide  = (const float*)d_in[0];
  const float* ybic   = (const float*)d_in[1];
  const float* source = (const float*)d_in[2];
  const float* mask   = (const float*)d_in[3];

  float* out   = (float*)d_out;
  float* ypred = out;                 // 524288
  float* cv    = out + NPIX;          // 523264
  float* ch    = out + NPIX + CVN;    // 523264

  float* ws = (float*)d_ws;
  float* hbuf0 = ws;                  // 512 tiles x 128 floats = 256 KB
  float* hbuf1 = ws + NTILES * 128;   // another 256 KB

  cvch_kernel<<<dim3((NPIX + 255) / 256), dim3(256), 0, stream>>>(ybic, guide, cv, ch);

  void* args[] = {(void*)&ybic, (void*)&ypred, (void*)&cv, (void*)&ch,
                  (void*)&source, (void*)&mask, (void*)&hbuf0, (void*)&hbuf1};
  hipLaunchCooperativeKernel((const void*)diffuse_all, dim3(NTILES), dim3(64),
                             args, 0, stream);
}

// Round 3
// 2628.091 us; speedup vs baseline: 2.7328x; 2.7328x over previous
//
#include <hip/hip_runtime.h>

// GADBase diffusion: B=2, H=W=512, 128 iterations of fused diffuse+adjust.
// Temporal blocking: each launch advances 8 steps on 32x64 output tiles using
// a 96x128 input region in LDS (redundant halo compute, ping-pong buffers).
constexpr int Hh = 512, Ww = 512, Bn = 2;
constexpr int SWs = 128;                  // source/mask spatial size
constexpr float Lf = 0.24f;
constexpr float Kf = 0.03f;
constexpr float EPSf = 1e-8f;
constexpr int NSTEPS = 128;

constexpr int NPIX = Bn * Hh * Ww;        // 524288
constexpr int CVN  = Bn * (Hh - 1) * Ww;  // 523264

constexpr int OTY = 32, OTX = 64, HALO = 32;
constexpr int RY = OTY + 2 * HALO;        // 96 region rows
constexpr int RX = OTX + 2 * HALO;        // 128 region cols
constexpr int SR = RX + 4;                // 132 LDS stride
constexpr int KSTEPS = 8;
constexpr int NLAUNCH = NSTEPS / KSTEPS;  // 16
constexpr int NWG = Bn * (Hh / OTY) * (Ww / OTX);  // 2*16*8 = 256

// ---------------------------------------------------------------------------
// Kernel 1: edge-stopping coefficients cv, ch (once, into d_out slots).
// ---------------------------------------------------------------------------
__global__ __launch_bounds__(256) void cvch_kernel(
    const float* __restrict__ img, const float* __restrict__ guide,
    float* __restrict__ cv, float* __restrict__ ch) {
  int idx = blockIdx.x * blockDim.x + threadIdx.x;
  if (idx >= NPIX) return;
  int x = idx & (Ww - 1);
  int y = (idx >> 9) & (Hh - 1);
  int b = idx >> 18;
  const float inv_k2 = 1.0f / (Kf * Kf);
  const float* f0 = img + (size_t)b * Hh * Ww;
  const float* g0 = guide + (size_t)b * 3 * Hh * Ww;
  const float* g1 = g0 + Hh * Ww;
  const float* g2 = g1 + Hh * Ww;
  int p = y * Ww + x;
  float c0 = f0[p], c1 = g0[p], c2 = g1[p], c3 = g2[p];
  if (y < Hh - 1) {
    int q = p + Ww;
    float m = (fabsf(f0[q] - c0) + fabsf(g0[q] - c1) +
               fabsf(g1[q] - c2) + fabsf(g2[q] - c3)) * 0.25f;
    cv[(b * (Hh - 1) + y) * Ww + x] = 1.0f / (1.0f + m * m * inv_k2);
  }
  if (x < Ww - 1) {
    int q = p + 1;
    float m = (fabsf(f0[q] - c0) + fabsf(g0[q] - c1) +
               fabsf(g1[q] - c2) + fabsf(g2[q] - c3)) * 0.25f;
    ch[(b * Hh + y) * (Ww - 1) + x] = 1.0f / (1.0f + m * m * inv_k2);
  }
}

// ---------------------------------------------------------------------------
// Kernel 2: 8 diffusion steps with shrinking valid region.
// 256 threads; 16 lanes per 4x4 block (lane = one pixel), 4 vertically
// adjacent blocks per wave -> every LDS access is at most 2-way (free).
// Valid region shrinks 4 px/side/step except at image borders (exact BC via
// zero coefficients). Out-of-image LDS cells: zeroed, weight 0 -> inert.
// ---------------------------------------------------------------------------
__global__ __launch_bounds__(256) void diffuse8_kernel(
    const float* __restrict__ src, float* __restrict__ dst,
    const float* __restrict__ cv, const float* __restrict__ ch,
    const float* __restrict__ source, const float* __restrict__ mask) {
  __shared__ float sbuf[2][RY * SR];

  int wg = blockIdx.x;
  int b  = wg >> 7;                 // 128 tiles per image
  int t  = wg & 127;
  int Ty0 = (t >> 3) * OTY;         // 16 tile rows
  int Tx0 = (t & 7) * OTX;          // 8 tile cols

  int tid  = threadIdx.x;
  int lane = tid & 63;
  int wv   = tid >> 6;
  int r    = (lane >> 2) & 3;       // pixel row in block
  int c    = lane & 3;              // pixel col in block
  int sub  = lane >> 4;             // which of 4 blocks in this wave

  const size_t ib = (size_t)b * Hh * Ww;
  const float* S   = src + ib;
  float*       G   = dst + ib;
  const float* cvb = cv + (size_t)b * (Hh - 1) * Ww;
  const float* chb = ch + (size_t)b * Hh * (Ww - 1);

  // Zero both buffers (frame cells must be finite), then load region.
  for (int m = tid; m < 2 * RY * SR; m += 256) (&sbuf[0][0])[m] = 0.0f;
  __syncthreads();
  for (int m = tid; m < RY * RX; m += 256) {
    int ly = m >> 7, lx = m & (RX - 1);
    int gy = Ty0 - HALO + ly; gy = max(0, min(Hh - 1, gy));
    int gx = Tx0 - HALO + lx; gx = max(0, min(Ww - 1, gx));
    sbuf[0][ly * SR + lx] = S[gy * Ww + gx];
  }

  for (int s = 0; s < KSTEPS; ++s) {
    __syncthreads();
    const float* A = sbuf[s & 1];
    float* Bb = sbuf[(s & 1) ^ 1];
    int u = s + 1;
    int y0 = max(0, Ty0 - HALO + 4 * u);
    int y1 = min(Hh, Ty0 + OTY + HALO - 4 * u);
    int x0 = max(0, Tx0 - HALO + 4 * u);
    int x1 = min(Ww, Tx0 + OTX + HALO - 4 * u);
    int nby = (y1 - y0) >> 2;
    int nbx = (x1 - x0) >> 2;
    int nb = nby * nbx;
    int nq = (nb + 3) >> 2;
    bool last = (s == KSTEPS - 1);

    for (int q = wv; q < nq; q += 4) {
      int j = q * 4 + sub;
      bool act = j < nb;
      int jj = act ? j : nb - 1;
      int by = jj % nby, bx = jj / nby;   // column-major: vertical blocks/wave
      int gy = y0 + by * 4 + r;
      int gx = x0 + bx * 4 + c;
      int ly = gy - Ty0 + HALO, lx = gx - Tx0 + HALO;
      int o = ly * SR + lx;

      float cc = A[o];
      float up = A[o - SR], dn = A[o + SR];
      float lf = A[o - 1],  rt = A[o + 1];
      float cu = (gy > 0)      ? Lf * cvb[(gy - 1) * Ww + gx]     : 0.0f;
      float cd = (gy < Hh - 1) ? Lf * cvb[gy * Ww + gx]           : 0.0f;
      float cl = (gx > 0)      ? Lf * chb[gy * (Ww - 1) + gx - 1] : 0.0f;
      float cr = (gx < Ww - 1) ? Lf * chb[gy * (Ww - 1) + gx]     : 0.0f;

      float acc = cc + cd * (dn - cc);
      acc -= cu * (cc - up);
      acc += cr * (rt - cc);
      acc -= cl * (cc - lf);

      // block mean over the 16 lanes of this sub-block
      float sum = acc;
      sum += __shfl_xor(sum, 1);
      sum += __shfl_xor(sum, 2);
      sum += __shfl_xor(sum, 4);
      sum += __shfl_xor(sum, 8);
      int sidx = (b * SWs + (gy >> 2)) * SWs + (gx >> 2);
      float ratio = (mask[sidx] > 0.5f)
                        ? 1.0f
                        : source[sidx] / (sum * (1.0f / 16.0f) + EPSf);
      float val = acc * ratio;

      if (act) {
        if (last) G[gy * Ww + gx] = val;   // G_8 == output tile exactly
        else      Bb[o] = val;
      }
    }
  }
}

// ---------------------------------------------------------------------------
// Fallback (ws too small for double buffer): one launch per step (round-1).
// ---------------------------------------------------------------------------
constexpr int FT = 32;
__global__ __launch_bounds__(64) void step_kernel(
    const float* __restrict__ src, float* __restrict__ dst,
    const float* __restrict__ cv, const float* __restrict__ ch,
    const float* __restrict__ source, const float* __restrict__ mask) {
  __shared__ float sI[FT + 2][FT + 3];
  int b = blockIdx.z;
  int ty0 = blockIdx.y * FT, tx0 = blockIdx.x * FT;
  const float* I = src + (size_t)b * Hh * Ww;
  int tid = threadIdx.x;
  for (int i = tid; i < (FT + 2) * (FT + 2); i += 64) {
    int ly = i / (FT + 2), lx = i % (FT + 2);
    int gy = max(0, min(Hh - 1, ty0 + ly - 1));
    int gx = max(0, min(Ww - 1, tx0 + lx - 1));
    sI[ly][lx] = I[gy * Ww + gx];
  }
  __syncthreads();
  int bby = tid >> 3, bbx = tid & 7;
  int py0 = bby * 4, px0 = bbx * 4;
  int gy0 = ty0 + py0, gx0 = tx0 + px0;
  const float* cvb = cv + (size_t)b * (Hh - 1) * Ww;
  const float* chb = ch + (size_t)b * Hh * (Ww - 1);
  float v[4][4]; float sum = 0.0f;
#pragma unroll
  for (int dy = 0; dy < 4; ++dy) {
    int y = gy0 + dy, ly = py0 + dy + 1;
#pragma unroll
    for (int dx = 0; dx < 4; ++dx) {
      int x = gx0 + dx, lx = px0 + dx + 1;
      float cc = sI[ly][lx];
      float acc = cc;
      if (y < Hh - 1) acc += Lf * cvb[y * Ww + x] * (sI[ly + 1][lx] - cc);
      if (y > 0)      acc -= Lf * cvb[(y - 1) * Ww + x] * (cc - sI[ly - 1][lx]);
      if (x < Ww - 1) acc += Lf * chb[y * (Ww - 1) + x] * (sI[ly][lx + 1] - cc);
      if (x > 0)      acc -= Lf * chb[y * (Ww - 1) + x - 1] * (cc - sI[ly][lx - 1]);
      v[dy][dx] = acc; sum += acc;
    }
  }
  int sidx = (b * SWs + (gy0 >> 2)) * SWs + (gx0 >> 2);
  float ratio = (mask[sidx] > 0.5f) ? 1.0f : source[sidx] / (sum * 0.0625f + EPSf);
  float* D = dst + (size_t)b * Hh * Ww;
#pragma unroll
  for (int dy = 0; dy < 4; ++dy)
    *reinterpret_cast<float4*>(&D[(gy0 + dy) * Ww + gx0]) =
        make_float4(v[dy][0] * ratio, v[dy][1] * ratio,
                    v[dy][2] * ratio, v[dy][3] * ratio);
}

// ---------------------------------------------------------------------------
extern "C" void kernel_launch(void* const* d_in, const int* in_sizes, int n_in,
                              void* d_out, int out_size, void* d_ws, size_t ws_size,
                              hipStream_t stream) {
  const float* guide  = (const float*)d_in[0];
  const float* ybic   = (const float*)d_in[1];
  const float* source = (const float*)d_in[2];
  const float* mask   = (const float*)d_in[3];

  float* out   = (float*)d_out;
  float* ypred = out;                 // 524288
  float* cv    = out + NPIX;          // 523264
  float* ch    = out + NPIX + CVN;    // 523264

  cvch_kernel<<<dim3((NPIX + 255) / 256), dim3(256), 0, stream>>>(ybic, guide, cv, ch);

  if (ws_size >= (size_t)2 * NPIX * sizeof(float)) {
    // Fast path: 16 launches x 8 steps, global ping-pong in ws.
    float* wsb0 = (float*)d_ws;
    float* wsb1 = wsb0 + NPIX;
    const float* sp = ybic;
    for (int l = 0; l < NLAUNCH; ++l) {
      float* dp = (l == NLAUNCH - 1) ? ypred : ((l & 1) ? wsb1 : wsb0);
      diffuse8_kernel<<<dim3(NWG), dim3(256), 0, stream>>>(sp, dp, cv, ch, source, mask);
      sp = dp;
    }
  } else {
    // Fallback: 128 single-step launches (needs only 2 MB ws).
    float* wsbuf = (float*)d_ws;
    dim3 grid(Ww / FT, Hh / FT, Bn);
    const float* sp = ybic;
    for (int it = 0; it < NSTEPS; ++it) {
      float* dp = (it & 1) ? ypred : wsbuf;
      step_kernel<<<grid, dim3(64), 0, stream>>>(sp, dp, cv, ch, source, mask);
      sp = dp;
    }
  }
}

// Round 4
// 454.826 us; speedup vs baseline: 15.7908x; 5.7782x over previous
//
#include <hip/hip_runtime.h>

// GADBase diffusion: B=2, H=W=512, 128 iterations of fused diffuse+adjust.
// Temporal blocking: each launch advances 4 steps on 32x32 output tiles using
// a 64x64 region in LDS. Coefficients L*cv, L*ch staged in LDS once/launch.
constexpr int Hh = 512, Ww = 512, Bn = 2;
constexpr int SWs = 128;
constexpr float Lf = 0.24f;
constexpr float Kf = 0.03f;
constexpr float EPSf = 1e-8f;
constexpr int NSTEPS = 128;

constexpr int NPIX = Bn * Hh * Ww;        // 524288
constexpr int CVN  = Bn * (Hh - 1) * Ww;  // 523264

constexpr int OT = 32, HALO = 16;
constexpr int RG = OT + 2 * HALO;         // 64 region side
constexpr int SR = 68;                    // LDS row stride (2-way max conflicts)
constexpr int KS = 4;
constexpr int NLAUNCH = NSTEPS / KS;      // 32
constexpr int NWG = Bn * (Hh / OT) * (Ww / OT);  // 2*16*16 = 512

// ---------------------------------------------------------------------------
// Kernel 1: edge-stopping coefficients cv, ch (once, into d_out slots).
// ---------------------------------------------------------------------------
__global__ __launch_bounds__(256) void cvch_kernel(
    const float* __restrict__ img, const float* __restrict__ guide,
    float* __restrict__ cv, float* __restrict__ ch) {
  int idx = blockIdx.x * blockDim.x + threadIdx.x;
  if (idx >= NPIX) return;
  int x = idx & (Ww - 1);
  int y = (idx >> 9) & (Hh - 1);
  int b = idx >> 18;
  const float inv_k2 = 1.0f / (Kf * Kf);
  const float* f0 = img + (size_t)b * Hh * Ww;
  const float* g0 = guide + (size_t)b * 3 * Hh * Ww;
  const float* g1 = g0 + Hh * Ww;
  const float* g2 = g1 + Hh * Ww;
  int p = y * Ww + x;
  float c0 = f0[p], c1 = g0[p], c2 = g1[p], c3 = g2[p];
  if (y < Hh - 1) {
    int q = p + Ww;
    float m = (fabsf(f0[q] - c0) + fabsf(g0[q] - c1) +
               fabsf(g1[q] - c2) + fabsf(g2[q] - c3)) * 0.25f;
    cv[(b * (Hh - 1) + y) * Ww + x] = 1.0f / (1.0f + m * m * inv_k2);
  }
  if (x < Ww - 1) {
    int q = p + 1;
    float m = (fabsf(f0[q] - c0) + fabsf(g0[q] - c1) +
               fabsf(g1[q] - c2) + fabsf(g2[q] - c3)) * 0.25f;
    ch[(b * Hh + y) * (Ww - 1) + x] = 1.0f / (1.0f + m * m * inv_k2);
  }
}

// ---------------------------------------------------------------------------
// Kernel 2: 4 diffusion+adjust steps per launch.
// 512 threads (8 waves), 2 WG/CU (68.3 KB LDS). 16 lanes per 4x4 block,
// 4 vertically-consecutive blocks per wave -> every LDS access <=2-way.
// Step geometry is compile-time (shrinking rectangles, no clipping: off-image
// pixels are decoupled because image-boundary coefficients are exactly 0).
// ---------------------------------------------------------------------------
__global__ __launch_bounds__(512, 4) void diffuse4_kernel(
    const float* __restrict__ src, float* __restrict__ dst,
    const float* __restrict__ cv, const float* __restrict__ ch,
    const float* __restrict__ source, const float* __restrict__ mask) {
  __shared__ float sI[2][RG * SR];          // 2 x 64x68
  __shared__ float sCV[(RG + 1) * SR];      // rows Ty0-1..Ty0+63 of L*cv
  __shared__ float sCH[RG * SR];            // cols Tx0-1..Tx0+63 of L*ch

  int wg = blockIdx.x;
  int b = wg >> 8;                          // 256 tiles per image
  int t = wg & 255;
  int Ty0 = (t >> 4) * OT - HALO;           // region origin (global row)
  int Tx0 = (t & 15) * OT - HALO;           // region origin (global col)

  int tid = threadIdx.x;
  const size_t ib = (size_t)b * Hh * Ww;
  const float* S = src + ib;
  float* G = dst + ib;
  const float* cvb = cv + (size_t)b * (Hh - 1) * Ww;
  const float* chb = ch + (size_t)b * Hh * (Ww - 1);

  // --- stage I region (coords clamped; off-image values are decoupled) ---
  for (int m = tid; m < RG * RG; m += 512) {
    int ly = m >> 6, lx = m & 63;
    int gy = min(max(Ty0 + ly, 0), Hh - 1);
    int gx = min(max(Tx0 + lx, 0), Ww - 1);
    sI[0][ly * SR + lx] = S[gy * Ww + gx];
  }
  // --- stage L*cv: row ly <-> global edge row Ty0-1+ly ---
  for (int m = tid; m < (RG + 1) * RG; m += 512) {
    int ly = m >> 6, lx = m & 63;
    int gy = Ty0 - 1 + ly;
    int gx = Tx0 + lx;
    float vv = 0.0f;
    if (gy >= 0 && gy < Hh - 1 && gx >= 0 && gx < Ww)
      vv = Lf * cvb[gy * Ww + gx];
    sCV[ly * SR + lx] = vv;
  }
  // --- stage L*ch: col lx <-> global edge col Tx0-1+lx ---
  for (int m = tid; m < RG * (RG + 1); m += 512) {
    int ly = m / (RG + 1), lx = m % (RG + 1);
    int gy = Ty0 + ly;
    int gx = Tx0 - 1 + lx;
    float vv = 0.0f;
    if (gy >= 0 && gy < Hh && gx >= 0 && gx < Ww - 1)
      vv = Lf * chb[gy * (Ww - 1) + gx];
    sCH[ly * SR + lx] = vv;
  }

  int lane16 = tid & 15;
  int r = lane16 >> 2, c = lane16 & 3;      // pixel in 4x4 block
  int bslot = tid >> 4;                     // 0..31 (4 consecutive per wave)

#pragma unroll
  for (int s = 0; s < KS; ++s) {
    __syncthreads();
    const float* A = sI[s & 1];
    float* Bb = sI[(s & 1) ^ 1];
    const int off = 4 * (s + 1);            // region-local rect start
    const int sz = RG - 8 * (s + 1);        // 56,48,40,32
    const int nby = sz >> 2;                // 14,12,10,8
    const int nb = nby * nby;               // 196,144,100,64
    const int NIT = (nb + 31) >> 5;         // 7,5,4,2
    const bool last = (s == KS - 1);

#pragma unroll
    for (int it = 0; it < NIT; ++it) {
      int j = it * 32 + bslot;
      if (j < nb) {
        int by = j % nby;                   // vertical-major (const divisor)
        int bx = j / nby;
        int ry = off + by * 4 + r;
        int rx = off + bx * 4 + c;
        int o = ry * SR + rx;

        float cc = A[o];
        float up = A[o - SR], dn = A[o + SR];
        float lf = A[o - 1],  rt = A[o + 1];
        float cu = sCV[o];                  // L*cv[gy-1, gx]
        float cd = sCV[o + SR];             // L*cv[gy,   gx]
        float cl = sCH[o];                  // L*ch[gy, gx-1]
        float cr = sCH[o + 1];              // L*ch[gy, gx  ]

        float acc = cc + cd * (dn - cc);
        acc -= cu * (cc - up);
        acc += cr * (rt - cc);
        acc -= cl * (cc - lf);

        float sum = acc;
        sum += __shfl_xor(sum, 1);
        sum += __shfl_xor(sum, 2);
        sum += __shfl_xor(sum, 4);
        sum += __shfl_xor(sum, 8);

        int gy = Ty0 + ry, gx = Tx0 + rx;
        int sy = min(max(gy >> 2, 0), SWs - 1);
        int sx = min(max(gx >> 2, 0), SWs - 1);
        int sidx = (b * SWs + sy) * SWs + sx;
        float ratio = (mask[sidx] > 0.5f)
                          ? 1.0f
                          : __fdividef(source[sidx], sum * 0.0625f + EPSf);
        float val = acc * ratio;

        if (last) G[gy * Ww + gx] = val;    // final rect == output tile
        else      Bb[o] = val;
      }
    }
  }
}

// ---------------------------------------------------------------------------
// Fallback (small ws): one launch per step.
// ---------------------------------------------------------------------------
constexpr int FT = 32;
__global__ __launch_bounds__(64) void step_kernel(
    const float* __restrict__ src, float* __restrict__ dst,
    const float* __restrict__ cv, const float* __restrict__ ch,
    const float* __restrict__ source, const float* __restrict__ mask) {
  __shared__ float sIl[FT + 2][FT + 3];
  int b = blockIdx.z;
  int ty0 = blockIdx.y * FT, tx0 = blockIdx.x * FT;
  const float* I = src + (size_t)b * Hh * Ww;
  int tid = threadIdx.x;
  for (int i = tid; i < (FT + 2) * (FT + 2); i += 64) {
    int ly = i / (FT + 2), lx = i % (FT + 2);
    int gy = max(0, min(Hh - 1, ty0 + ly - 1));
    int gx = max(0, min(Ww - 1, tx0 + lx - 1));
    sIl[ly][lx] = I[gy * Ww + gx];
  }
  __syncthreads();
  int bby = tid >> 3, bbx = tid & 7;
  int py0 = bby * 4, px0 = bbx * 4;
  int gy0 = ty0 + py0, gx0 = tx0 + px0;
  const float* cvb = cv + (size_t)b * (Hh - 1) * Ww;
  const float* chb = ch + (size_t)b * Hh * (Ww - 1);
  float v[4][4]; float sum = 0.0f;
#pragma unroll
  for (int dy = 0; dy < 4; ++dy) {
    int y = gy0 + dy, ly = py0 + dy + 1;
#pragma unroll
    for (int dx = 0; dx < 4; ++dx) {
      int x = gx0 + dx, lx = px0 + dx + 1;
      float cc = sIl[ly][lx];
      float acc = cc;
      if (y < Hh - 1) acc += Lf * cvb[y * Ww + x] * (sIl[ly + 1][lx] - cc);
      if (y > 0)      acc -= Lf * cvb[(y - 1) * Ww + x] * (cc - sIl[ly - 1][lx]);
      if (x < Ww - 1) acc += Lf * chb[y * (Ww - 1) + x] * (sIl[ly][lx + 1] - cc);
      if (x > 0)      acc -= Lf * chb[y * (Ww - 1) + x - 1] * (cc - sIl[ly][lx - 1]);
      v[dy][dx] = acc; sum += acc;
    }
  }
  int sidx = (b * SWs + (gy0 >> 2)) * SWs + (gx0 >> 2);
  float ratio = (mask[sidx] > 0.5f) ? 1.0f : source[sidx] / (sum * 0.0625f + EPSf);
  float* D = dst + (size_t)b * Hh * Ww;
#pragma unroll
  for (int dy = 0; dy < 4; ++dy)
    *reinterpret_cast<float4*>(&D[(gy0 + dy) * Ww + gx0]) =
        make_float4(v[dy][0] * ratio, v[dy][1] * ratio,
                    v[dy][2] * ratio, v[dy][3] * ratio);
}

// ---------------------------------------------------------------------------
extern "C" void kernel_launch(void* const* d_in, const int* in_sizes, int n_in,
                              void* d_out, int out_size, void* d_ws, size_t ws_size,
                              hipStream_t stream) {
  const float* guide  = (const float*)d_in[0];
  const float* ybic   = (const float*)d_in[1];
  const float* source = (const float*)d_in[2];
  const float* mask   = (const float*)d_in[3];

  float* out   = (float*)d_out;
  float* ypred = out;                 // 524288
  float* cv    = out + NPIX;          // 523264
  float* ch    = out + NPIX + CVN;    // 523264

  cvch_kernel<<<dim3((NPIX + 255) / 256), dim3(256), 0, stream>>>(ybic, guide, cv, ch);

  if (ws_size >= (size_t)2 * NPIX * sizeof(float)) {
    float* wsb0 = (float*)d_ws;
    float* wsb1 = wsb0 + NPIX;
    const float* sp = ybic;
    for (int l = 0; l < NLAUNCH; ++l) {
      float* dp = (l == NLAUNCH - 1) ? ypred : ((l & 1) ? wsb1 : wsb0);
      diffuse4_kernel<<<dim3(NWG), dim3(512), 0, stream>>>(sp, dp, cv, ch, source, mask);
      sp = dp;
    }
  } else {
    float* wsbuf = (float*)d_ws;
    dim3 grid(Ww / FT, Hh / FT, Bn);
    const float* sp = ybic;
    for (int it = 0; it < NSTEPS; ++it) {
      float* dp = (it & 1) ? ypred : wsbuf;
      step_kernel<<<grid, dim3(64), 0, stream>>>(sp, dp, cv, ch, source, mask);
      sp = dp;
    }
  }
}

// Round 5
// 330.295 us; speedup vs baseline: 21.7444x; 1.3770x over previous
//
#include <hip/hip_runtime.h>

// GADBase diffusion: B=2, H=W=512, 128 iterations of fused diffuse+adjust.
// Register-resident temporal blocking: each thread owns one 4x4 block for a
// whole launch (KS=5 steps); only block edges go through LDS each step.
constexpr int Hh = 512, Ww = 512, Bn = 2;
constexpr int SWs = 128;
constexpr float Lf = 0.24f;
constexpr float Kf = 0.03f;
constexpr float EPSf = 1e-8f;
constexpr int NSTEPS = 128;

constexpr int NPIX = Bn * Hh * Ww;        // 524288
constexpr int CVN  = Bn * (Hh - 1) * Ww;  // 523264

constexpr int OT = 32;                    // output tile side
constexpr int KS = 5;                     // steps per launch
constexpr int HALO = 4 * KS;              // 20
constexpr int G = (OT + 2 * HALO) / 4;    // 18x18 block grid per region
constexpr int REC = 20;                   // edge record stride (dwords, padded)
constexpr int NREC = G * G;               // 324
constexpr int NWG = Bn * (Hh / OT) * (Ww / OT);  // 512

__device__ __forceinline__ int clampi(int v, int lo, int hi) {
  return min(max(v, lo), hi);
}

// ---------------------------------------------------------------------------
// Kernel 1: edge-stopping coefficients cv, ch (once, into d_out slots).
// ---------------------------------------------------------------------------
__global__ __launch_bounds__(256) void cvch_kernel(
    const float* __restrict__ img, const float* __restrict__ guide,
    float* __restrict__ cv, float* __restrict__ ch) {
  int idx = blockIdx.x * blockDim.x + threadIdx.x;
  if (idx >= NPIX) return;
  int x = idx & (Ww - 1);
  int y = (idx >> 9) & (Hh - 1);
  int b = idx >> 18;
  const float inv_k2 = 1.0f / (Kf * Kf);
  const float* f0 = img + (size_t)b * Hh * Ww;
  const float* g0 = guide + (size_t)b * 3 * Hh * Ww;
  const float* g1 = g0 + Hh * Ww;
  const float* g2 = g1 + Hh * Ww;
  int p = y * Ww + x;
  float c0 = f0[p], c1 = g0[p], c2 = g1[p], c3 = g2[p];
  if (y < Hh - 1) {
    int q = p + Ww;
    float m = (fabsf(f0[q] - c0) + fabsf(g0[q] - c1) +
               fabsf(g1[q] - c2) + fabsf(g2[q] - c3)) * 0.25f;
    cv[(b * (Hh - 1) + y) * Ww + x] = 1.0f / (1.0f + m * m * inv_k2);
  }
  if (x < Ww - 1) {
    int q = p + 1;
    float m = (fabsf(f0[q] - c0) + fabsf(g0[q] - c1) +
               fabsf(g1[q] - c2) + fabsf(g2[q] - c3)) * 0.25f;
    ch[(b * Hh + y) * (Ww - 1) + x] = 1.0f / (1.0f + m * m * inv_k2);
  }
}

// ---------------------------------------------------------------------------
// Kernel 2: up to 5 diffusion+adjust steps per launch, block state in regs.
// 256 threads = interior 16x16 blocks of an 18x18 block grid (72x72 region
// around a 32x32 output tile). Per step: 4 ds_write_b128 + 4 ds_read_b128.
// Shrinking-active-set schedule: step s computes blocks [s+1, 17-s)^2.
// Off-image pixels are decoupled (boundary-crossing coefficients exactly 0),
// values stay finite (clamped loads, positive dynamics).
// ---------------------------------------------------------------------------
__global__ __launch_bounds__(256, 3) void diffuse5_kernel(
    const float* __restrict__ src, float* __restrict__ dst,
    const float* __restrict__ cv, const float* __restrict__ ch,
    const float* __restrict__ source, const float* __restrict__ mask,
    int nsteps) {
  __shared__ __align__(16) float ebuf[NREC * REC];  // 25.9 KB

  int wg = blockIdx.x;
  int b  = wg >> 8;                        // 256 tiles per image
  int t  = wg & 255;
  int Ty0 = (t >> 4) * OT;
  int Tx0 = (t & 15) * OT;

  int tid = threadIdx.x;
  int by = 1 + (tid >> 4), bx = 1 + (tid & 15);
  int rec = (by * G + bx) * REC;
  int gy0 = Ty0 - HALO + 4 * by;           // block origin (may be off-image)
  int gx0 = Tx0 - HALO + 4 * bx;

  const size_t ib = (size_t)b * Hh * Ww;
  const float* S = src + ib;
  float* D = dst + ib;
  const float* cvb = cv + (size_t)b * (Hh - 1) * Ww;
  const float* chb = ch + (size_t)b * Hh * (Ww - 1);

  // clamped float4 row load from image (gx is a multiple of 4 -> a block row
  // is fully in-image or fully out per axis; out rows/cols splat clamped val)
  auto ld4 = [&](int gy, int gx) -> float4 {
    gy = clampi(gy, 0, Hh - 1);
    if (gx < 0)      { float v = S[gy * Ww];          return make_float4(v, v, v, v); }
    if (gx > Ww - 4) { float v = S[gy * Ww + Ww - 1]; return make_float4(v, v, v, v); }
    return *reinterpret_cast<const float4*>(&S[gy * Ww + gx]);
  };

  // --- own 4x4 block + initial neighbor edges (time 0) ---
  float I[4][4], V[4][4];
  float nT[4], nB[4], nL[4], nR[4];
#pragma unroll
  for (int r = 0; r < 4; ++r) {
    float4 t4 = ld4(gy0 + r, gx0);
    I[r][0] = t4.x; I[r][1] = t4.y; I[r][2] = t4.z; I[r][3] = t4.w;
  }
  {
    float4 t4 = ld4(gy0 - 1, gx0);
    nT[0] = t4.x; nT[1] = t4.y; nT[2] = t4.z; nT[3] = t4.w;
    t4 = ld4(gy0 + 4, gx0);
    nB[0] = t4.x; nB[1] = t4.y; nB[2] = t4.z; nB[3] = t4.w;
  }
#pragma unroll
  for (int r = 0; r < 4; ++r) {
    int gy = clampi(gy0 + r, 0, Hh - 1);
    nL[r] = S[gy * Ww + clampi(gx0 - 1, 0, Ww - 1)];
    nR[r] = S[gy * Ww + clampi(gx0 + 4, 0, Ww - 1)];
  }

  // --- step-invariant coefficients (L folded in; boundary edges -> 0) ---
  float cvk[5][4];                         // edge rows gy0-1 .. gy0+3
#pragma unroll
  for (int k = 0; k < 5; ++k) {
    int ro = gy0 - 1 + k;
    if (ro < 0 || ro > Hh - 2) {
      cvk[k][0] = cvk[k][1] = cvk[k][2] = cvk[k][3] = 0.0f;
    } else if (gx0 < 0) {
      float v = Lf * cvb[ro * Ww];
      cvk[k][0] = cvk[k][1] = cvk[k][2] = cvk[k][3] = v;
    } else if (gx0 > Ww - 4) {
      float v = Lf * cvb[ro * Ww + Ww - 1];
      cvk[k][0] = cvk[k][1] = cvk[k][2] = cvk[k][3] = v;
    } else {
      float4 t4 = *reinterpret_cast<const float4*>(&cvb[ro * Ww + gx0]);
      cvk[k][0] = Lf * t4.x; cvk[k][1] = Lf * t4.y;
      cvk[k][2] = Lf * t4.z; cvk[k][3] = Lf * t4.w;
    }
  }
  float chk[4][5];                         // edge cols gx0-1 .. gx0+3
#pragma unroll
  for (int r = 0; r < 4; ++r) {
    int ri = clampi(gy0 + r, 0, Hh - 1);
#pragma unroll
    for (int j = 0; j < 5; ++j) {
      int e = gx0 - 1 + j;
      chk[r][j] = (e >= 0 && e <= Ww - 2) ? Lf * chb[ri * (Ww - 1) + e] : 0.0f;
    }
  }

  int sy = clampi(gy0 >> 2, 0, SWs - 1);
  int sx = clampi(gx0 >> 2, 0, SWs - 1);
  int sidx = (b * SWs + sy) * SWs + sx;
  float srcv = source[sidx];
  bool mskv = mask[sidx] > 0.5f;

#pragma unroll
  for (int s = 0; s < KS; ++s) {
    if (s >= nsteps) break;
    if (s > 0) {
      __syncthreads();
      float4 t4;
      t4 = *reinterpret_cast<const float4*>(&ebuf[rec - G * REC + 4]);  // up's bottom
      nT[0] = t4.x; nT[1] = t4.y; nT[2] = t4.z; nT[3] = t4.w;
      t4 = *reinterpret_cast<const float4*>(&ebuf[rec + G * REC + 0]);  // down's top
      nB[0] = t4.x; nB[1] = t4.y; nB[2] = t4.z; nB[3] = t4.w;
      t4 = *reinterpret_cast<const float4*>(&ebuf[rec - REC + 12]);     // left's right
      nL[0] = t4.x; nL[1] = t4.y; nL[2] = t4.z; nL[3] = t4.w;
      t4 = *reinterpret_cast<const float4*>(&ebuf[rec + REC + 8]);      // right's left
      nR[0] = t4.x; nR[1] = t4.y; nR[2] = t4.z; nR[3] = t4.w;
    }

    float sum = 0.0f;
#pragma unroll
    for (int r = 0; r < 4; ++r)
#pragma unroll
      for (int c = 0; c < 4; ++c) {
        float cc = I[r][c];
        float up = (r == 0) ? nT[c] : I[r - 1][c];
        float dn = (r == 3) ? nB[c] : I[r + 1][c];
        float lf = (c == 0) ? nL[r] : I[r][c - 1];
        float rt = (c == 3) ? nR[r] : I[r][c + 1];
        float acc = cc + cvk[r + 1][c] * (dn - cc) - cvk[r][c] * (cc - up)
                       + chk[r][c + 1] * (rt - cc) - chk[r][c] * (cc - lf);
        V[r][c] = acc;
        sum += acc;
      }

    float ratio = mskv ? 1.0f : srcv / (sum * 0.0625f + EPSf);
#pragma unroll
    for (int r = 0; r < 4; ++r)
#pragma unroll
      for (int c = 0; c < 4; ++c) V[r][c] *= ratio;

    if (s == nsteps - 1) {
      // final values -> global (central 8x8 blocks == the 32x32 output tile)
      if (by >= 5 && by < 13 && bx >= 5 && bx < 13) {
#pragma unroll
        for (int r = 0; r < 4; ++r)
          *reinterpret_cast<float4*>(&D[(gy0 + r) * Ww + gx0]) =
              make_float4(V[r][0], V[r][1], V[r][2], V[r][3]);
      }
    } else {
      __syncthreads();
      // publish edges needed by step s+1 readers (active set of step s)
      if (by > s && by < G - 1 - s && bx > s && bx < G - 1 - s) {
        *reinterpret_cast<float4*>(&ebuf[rec + 0]) =
            make_float4(V[0][0], V[0][1], V[0][2], V[0][3]);       // top row
        *reinterpret_cast<float4*>(&ebuf[rec + 4]) =
            make_float4(V[3][0], V[3][1], V[3][2], V[3][3]);       // bottom row
        *reinterpret_cast<float4*>(&ebuf[rec + 8]) =
            make_float4(V[0][0], V[1][0], V[2][0], V[3][0]);       // left col
        *reinterpret_cast<float4*>(&ebuf[rec + 12]) =
            make_float4(V[0][3], V[1][3], V[2][3], V[3][3]);       // right col
      }
    }

#pragma unroll
    for (int r = 0; r < 4; ++r)
#pragma unroll
      for (int c = 0; c < 4; ++c) I[r][c] = V[r][c];
  }
}

// ---------------------------------------------------------------------------
// Fallback (small ws): one launch per step.
// ---------------------------------------------------------------------------
constexpr int FT = 32;
__global__ __launch_bounds__(64) void step_kernel(
    const float* __restrict__ src, float* __restrict__ dst,
    const float* __restrict__ cv, const float* __restrict__ ch,
    const float* __restrict__ source, const float* __restrict__ mask) {
  __shared__ float sIl[FT + 2][FT + 3];
  int b = blockIdx.z;
  int ty0 = blockIdx.y * FT, tx0 = blockIdx.x * FT;
  const float* I = src + (size_t)b * Hh * Ww;
  int tid = threadIdx.x;
  for (int i = tid; i < (FT + 2) * (FT + 2); i += 64) {
    int ly = i / (FT + 2), lx = i % (FT + 2);
    int gy = max(0, min(Hh - 1, ty0 + ly - 1));
    int gx = max(0, min(Ww - 1, tx0 + lx - 1));
    sIl[ly][lx] = I[gy * Ww + gx];
  }
  __syncthreads();
  int bby = tid >> 3, bbx = tid & 7;
  int py0 = bby * 4, px0 = bbx * 4;
  int gy0 = ty0 + py0, gx0 = tx0 + px0;
  const float* cvb = cv + (size_t)b * (Hh - 1) * Ww;
  const float* chb = ch + (size_t)b * Hh * (Ww - 1);
  float v[4][4]; float sum = 0.0f;
#pragma unroll
  for (int dy = 0; dy < 4; ++dy) {
    int y = gy0 + dy, ly = py0 + dy + 1;
#pragma unroll
    for (int dx = 0; dx < 4; ++dx) {
      int x = gx0 + dx, lx = px0 + dx + 1;
      float cc = sIl[ly][lx];
      float acc = cc;
      if (y < Hh - 1) acc += Lf * cvb[y * Ww + x] * (sIl[ly + 1][lx] - cc);
      if (y > 0)      acc -= Lf * cvb[(y - 1) * Ww + x] * (cc - sIl[ly - 1][lx]);
      if (x < Ww - 1) acc += Lf * chb[y * (Ww - 1) + x] * (sIl[ly][lx + 1] - cc);
      if (x > 0)      acc -= Lf * chb[y * (Ww - 1) + x - 1] * (cc - sIl[ly][lx - 1]);
      v[dy][dx] = acc; sum += acc;
    }
  }
  int sidx = (b * SWs + (gy0 >> 2)) * SWs + (gx0 >> 2);
  float ratio = (mask[sidx] > 0.5f) ? 1.0f : source[sidx] / (sum * 0.0625f + EPSf);
  float* D = dst + (size_t)b * Hh * Ww;
#pragma unroll
  for (int dy = 0; dy < 4; ++dy)
    *reinterpret_cast<float4*>(&D[(gy0 + dy) * Ww + gx0]) =
        make_float4(v[dy][0] * ratio, v[dy][1] * ratio,
                    v[dy][2] * ratio, v[dy][3] * ratio);
}

// ---------------------------------------------------------------------------
extern "C" void kernel_launch(void* const* d_in, const int* in_sizes, int n_in,
                              void* d_out, int out_size, void* d_ws, size_t ws_size,
                              hipStream_t stream) {
  const float* guide  = (const float*)d_in[0];
  const float* ybic   = (const float*)d_in[1];
  const float* source = (const float*)d_in[2];
  const float* mask   = (const float*)d_in[3];

  float* out   = (float*)d_out;
  float* ypred = out;                 // 524288
  float* cv    = out + NPIX;          // 523264
  float* ch    = out + NPIX + CVN;    // 523264

  cvch_kernel<<<dim3((NPIX + 255) / 256), dim3(256), 0, stream>>>(ybic, guide, cv, ch);

  if (ws_size >= (size_t)2 * NPIX * sizeof(float)) {
    float* wsb0 = (float*)d_ws;
    float* wsb1 = wsb0 + NPIX;
    const float* sp = ybic;
    int done = 0, l = 0;
    while (done < NSTEPS) {
      int ns = (NSTEPS - done >= KS) ? KS : (NSTEPS - done);   // 25x5 + 1x3
      bool lastL = (done + ns == NSTEPS);
      float* dp = lastL ? ypred : ((l & 1) ? wsb1 : wsb0);
      diffuse5_kernel<<<dim3(NWG), dim3(256), 0, stream>>>(sp, dp, cv, ch,
                                                           source, mask, ns);
      sp = dp; done += ns; ++l;
    }
  } else {
    float* wsbuf = (float*)d_ws;
    dim3 grid(Ww / FT, Hh / FT, Bn);
    const float* sp = ybic;
    for (int it = 0; it < NSTEPS; ++it) {
      float* dp = (it & 1) ? ypred : wsbuf;
      step_kernel<<<grid, dim3(64), 0, stream>>>(sp, dp, cv, ch, source, mask);
      sp = dp;
    }
  }
}